// Round 1
// baseline (172.298 us; speedup 1.0000x reference)
//
#include <hip/hip_runtime.h>
#include <cstdint>

#define BB   16
#define NN   1024
#define FIN  128
#define FOUT 64
#define ALPHA_S 0.2f
#define MASK_VAL -1000000000000.0f

__device__ inline float wave_max(float v){
  #pragma unroll
  for (int off = 32; off; off >>= 1) v = fmaxf(v, __shfl_xor(v, off, 64));
  return v;
}
__device__ inline float wave_sum(float v){
  #pragma unroll
  for (int off = 32; off; off >>= 1) v += __shfl_xor(v, off, 64);
  return v;
}

// Kernel 1: h = inp @ W (fp32), s1 = h . a1, s2 = h . a2
// grid: B*N/4 blocks, 256 threads; wave w computes row (blockIdx*4 + w), lane = output feature.
__global__ __launch_bounds__(256) void k_proj(const float* __restrict__ inp,
                                              const float* __restrict__ W,
                                              const float* __restrict__ a,
                                              float* __restrict__ h,
                                              float* __restrict__ s1,
                                              float* __restrict__ s2){
  __shared__ float inp_s[4][FIN];   // 2 KB
  const int t = threadIdx.x;
  const int r = t >> 6;            // wave id 0..3 -> row within block
  const int f = t & 63;            // output feature
  const int row0 = blockIdx.x * 4; // global row in [0, B*N)

  for (int idx = t; idx < 4 * FIN; idx += 256){
    int rr = idx >> 7, k = idx & 127;
    inp_s[rr][k] = inp[(size_t)(row0 + rr) * FIN + k];
  }
  __syncthreads();

  float acc = 0.f;
  #pragma unroll 8
  for (int k = 0; k < FIN; k += 4){
    float4 iv = *(const float4*)&inp_s[r][k];
    acc = fmaf(iv.x, W[(k + 0) * FOUT + f], acc);
    acc = fmaf(iv.y, W[(k + 1) * FOUT + f], acc);
    acc = fmaf(iv.z, W[(k + 2) * FOUT + f], acc);
    acc = fmaf(iv.w, W[(k + 3) * FOUT + f], acc);
  }
  const int row = row0 + r;
  h[(size_t)row * FOUT + f] = acc;
  float v1 = wave_sum(acc * a[f]);
  float v2 = wave_sum(acc * a[FOUT + f]);
  if (f == 0){ s1[row] = v1; s2[row] = v2; }
}

// Kernel 2: fused masked-softmax attention + aggregation + ELU.
// grid: B*(N/4) blocks, 256 threads. Block handles rows i0..i0+3 of batch b.
__global__ __launch_bounds__(256) void k_attn(const int* __restrict__ adj,
                                              const float* __restrict__ h,
                                              const float* __restrict__ s1,
                                              const float* __restrict__ s2,
                                              float* __restrict__ out){
  __shared__ float p_buf[4][NN];   // 16 KB: softmax numerators per row
  __shared__ float red[4];
  __shared__ float l_s[4];
  const int t    = threadIdx.x;
  const int wid  = t >> 6;
  const int lane = t & 63;
  const int bi = blockIdx.x;       // 0 .. B*N/4-1
  const int b  = bi >> 8;          // N/4 = 256 blocks per batch
  const int i0 = (bi & 255) * 4;

  // s2 for this batch: each thread covers j = 4t..4t+3 (hoisted out of row loop)
  const float4 s2v = ((const float4*)(s2 + b * NN))[t];

  // ---- Phase A: scores -> softmax numerators p_buf, denominators l_s ----
  for (int r = 0; r < 4; ++r){
    const int i = i0 + r;
    const int4 a4 = ((const int4*)(adj + ((size_t)(b * NN + i)) * NN))[t];
    const float s1i = s1[b * NN + i];

    float e0 = s1i + s2v.x; e0 = e0 > 0.f ? e0 : ALPHA_S * e0; float sc0 = a4.x > 0 ? e0 : MASK_VAL;
    float e1 = s1i + s2v.y; e1 = e1 > 0.f ? e1 : ALPHA_S * e1; float sc1 = a4.y > 0 ? e1 : MASK_VAL;
    float e2 = s1i + s2v.z; e2 = e2 > 0.f ? e2 : ALPHA_S * e2; float sc2 = a4.z > 0 ? e2 : MASK_VAL;
    float e3 = s1i + s2v.w; e3 = e3 > 0.f ? e3 : ALPHA_S * e3; float sc3 = a4.w > 0 ? e3 : MASK_VAL;

    float m = wave_max(fmaxf(fmaxf(sc0, sc1), fmaxf(sc2, sc3)));
    if (lane == 0) red[wid] = m;
    __syncthreads();                                    // (1) maxes visible
    m = fmaxf(fmaxf(red[0], red[1]), fmaxf(red[2], red[3]));
    __syncthreads();                                    // (2) red reusable

    float p0 = __expf(sc0 - m);
    float p1 = __expf(sc1 - m);
    float p2 = __expf(sc2 - m);
    float p3 = __expf(sc3 - m);
    *(float4*)&p_buf[r][t * 4] = make_float4(p0, p1, p2, p3);

    float s = wave_sum(p0 + p1 + p2 + p3);
    if (lane == 0) red[wid] = s;
    __syncthreads();                                    // (3) sums visible
    if (t == 0) l_s[r] = 1.0f / (red[0] + red[1] + red[2] + red[3]);
    __syncthreads();                                    // (4) red reusable next row
  }

  // ---- Phase B: h_prime[r][f] = sum_j p[r][j] * h[b][j][f] ----
  const int f = lane;
  const int c = wid;               // j-chunk: 4 chunks of 256
  const float* hb = h + (size_t)b * NN * FOUT;
  float acc0 = 0.f, acc1 = 0.f, acc2 = 0.f, acc3 = 0.f;
  for (int jj = 0; jj < 256; jj += 4){
    const int j = c * 256 + jj;
    const float* hp = hb + (size_t)j * FOUT + f;
    float h0 = hp[0];
    float h1 = hp[64];
    float h2 = hp[128];
    float h3 = hp[192];
    float4 p;
    p = *(const float4*)&p_buf[0][j]; acc0 += p.x * h0 + p.y * h1 + p.z * h2 + p.w * h3;
    p = *(const float4*)&p_buf[1][j]; acc1 += p.x * h0 + p.y * h1 + p.z * h2 + p.w * h3;
    p = *(const float4*)&p_buf[2][j]; acc2 += p.x * h0 + p.y * h1 + p.z * h2 + p.w * h3;
    p = *(const float4*)&p_buf[3][j]; acc3 += p.x * h0 + p.y * h1 + p.z * h2 + p.w * h3;
  }
  __syncthreads();                 // p_buf dead; reuse as reduction scratch
  float* scratch = &p_buf[0][0];   // needs 4*4*64 = 1024 floats
  scratch[(0 * 4 + c) * 64 + f] = acc0;
  scratch[(1 * 4 + c) * 64 + f] = acc1;
  scratch[(2 * 4 + c) * 64 + f] = acc2;
  scratch[(3 * 4 + c) * 64 + f] = acc3;
  __syncthreads();
  {
    const int r = wid;             // thread t = r*64+f writes row i0+r, feature f
    float ssum = scratch[(r * 4 + 0) * 64 + f] + scratch[(r * 4 + 1) * 64 + f]
               + scratch[(r * 4 + 2) * 64 + f] + scratch[(r * 4 + 3) * 64 + f];
    float hpv = ssum * l_s[r];
    float o = hpv > 0.f ? hpv : __expf(hpv) - 1.0f;    // ELU (alpha=1)
    out[((size_t)(b * NN + i0 + r)) * FOUT + f] = o;
  }
}

extern "C" void kernel_launch(void* const* d_in, const int* in_sizes, int n_in,
                              void* d_out, int out_size, void* d_ws, size_t ws_size,
                              hipStream_t stream) {
  const float* inp = (const float*)d_in[0];   // (16,1024,128) fp32
  const int*   adj = (const int*)d_in[1];     // (16,1024,1024) int32
  const float* W   = (const float*)d_in[2];   // (128,64) fp32
  const float* a   = (const float*)d_in[3];   // (128,1) fp32
  float* outp = (float*)d_out;                // (16,1024,64) fp32

  float* h  = (float*)d_ws;                   // B*N*FOUT = 1,048,576 floats (4 MB)
  float* s1 = h + (size_t)BB * NN * FOUT;     // B*N floats
  float* s2 = s1 + (size_t)BB * NN;           // B*N floats

  k_proj<<<BB * NN / 4, 256, 0, stream>>>(inp, W, a, h, s1, s2);
  k_attn<<<BB * (NN / 4), 256, 0, stream>>>(adj, h, s1, s2, outp);
}

// Round 3
// 144.857 us; speedup vs baseline: 1.1894x; 1.1894x over previous
//
#include <hip/hip_runtime.h>
#include <cstdint>

#define BB   16
#define NN   1024
#define FIN  128
#define FOUT 64
#define ALPHA_S 0.2f
#define MASK_VAL -1000000000000.0f
#define PSTRIDE 1032   // 1024 + 8 f16 pad: rows stay 16B-aligned, banks spread

typedef float    f32x4 __attribute__((ext_vector_type(4)));
typedef _Float16 half8 __attribute__((ext_vector_type(8)));

__device__ inline float wave_max(float v){
  #pragma unroll
  for (int off = 32; off; off >>= 1) v = fmaxf(v, __shfl_xor(v, off, 64));
  return v;
}
__device__ inline float wave_sum(float v){
  #pragma unroll
  for (int off = 32; off; off >>= 1) v += __shfl_xor(v, off, 64);
  return v;
}

// ---------------------------------------------------------------------------
// Kernel 1: h = inp @ W; s1 = h.a1, s2 = h.a2; emit hT (f16 hi+lo) in
// K-tiled layout hT[b][kk][f][jj]  (kk = j>>5, jj = j&31), 32*64*32 per batch.
// Block = 256 threads, 16 rows; wave w owns rows 4w..4w+3, lane = f.
// ---------------------------------------------------------------------------
__global__ __launch_bounds__(256) void k_proj(const float* __restrict__ inp,
                                              const float* __restrict__ W,
                                              const float* __restrict__ a,
                                              _Float16* __restrict__ hT_hi,
                                              _Float16* __restrict__ hT_lo,
                                              float* __restrict__ s1,
                                              float* __restrict__ s2){
  const int t = threadIdx.x;
  const int w = t >> 6, f = t & 63;
  const int row0 = blockIdx.x * 16 + w * 4;
  const float* ip = inp + (size_t)row0 * FIN;
  const float a1f = a[f];
  const float a2f = a[FOUT + f];

  float acc0 = 0.f, acc1 = 0.f, acc2 = 0.f, acc3 = 0.f;
  #pragma unroll 4
  for (int k = 0; k < FIN; ++k){
    float wf = W[k * FOUT + f];
    acc0 = fmaf(ip[k],           wf, acc0);
    acc1 = fmaf(ip[FIN + k],     wf, acc1);
    acc2 = fmaf(ip[2 * FIN + k], wf, acc2);
    acc3 = fmaf(ip[3 * FIN + k], wf, acc3);
  }

  float accs[4] = {acc0, acc1, acc2, acc3};
  #pragma unroll
  for (int q = 0; q < 4; ++q){
    const int row = row0 + q;                 // global row in [0, B*N)
    const int b = row >> 10, j = row & 1023;
    float v = accs[q];
    float v1 = wave_sum(v * a1f);
    float v2 = wave_sum(v * a2f);
    if (f == 0){ s1[row] = v1; s2[row] = v2; }
    _Float16 hi = (_Float16)v;
    _Float16 lo = (_Float16)(v - (float)hi);
    size_t idx = (size_t)b * 65536 + (size_t)(j >> 5) * 2048 + (size_t)f * 32 + (j & 31);
    hT_hi[idx] = hi;
    hT_lo[idx] = lo;
  }
}

// ---------------------------------------------------------------------------
// Kernel 2: fused masked-softmax + MFMA aggregation + ELU.
// Block = 256 threads (4 waves), 16 rows of one batch. Grid = 16*64 = 1024.
// Phase A: wave w owns local rows 4w..4w+3 end-to-end (wave-local softmax
//          reductions, no cross-wave barrier per row); p -> f16 LDS.
// Phase B: wave w owns a 16-col tile; 32 K-steps x (1 A ds_read_b128 +
//          2 B global dwordx4 + 2 MFMA 16x16x32_f16 hi/lo).
// ---------------------------------------------------------------------------
__global__ __launch_bounds__(256) void k_attn(const int* __restrict__ adj,
                                              const _Float16* __restrict__ hT_hi,
                                              const _Float16* __restrict__ hT_lo,
                                              const float* __restrict__ s1,
                                              const float* __restrict__ s2,
                                              float* __restrict__ out){
  __shared__ _Float16 p_buf[16][PSTRIDE];   // ~33 KB
  __shared__ float inv_l[16];

  const int t = threadIdx.x;
  const int w = t >> 6, lane = t & 63;
  const int b  = blockIdx.x >> 6;          // 64 row-tiles per batch
  const int i0 = (blockIdx.x & 63) * 16;

  // s2 for j = lane*16 .. lane*16+15 (hoisted; reused for all 4 rows)
  float s2r[16];
  {
    const float4* s2p = (const float4*)(s2 + b * NN);
    #pragma unroll
    for (int c = 0; c < 4; ++c){
      float4 v = s2p[lane * 4 + c];
      s2r[c * 4 + 0] = v.x; s2r[c * 4 + 1] = v.y;
      s2r[c * 4 + 2] = v.z; s2r[c * 4 + 3] = v.w;
    }
  }

  // ---- Phase A ----
  #pragma unroll
  for (int rq = 0; rq < 4; ++rq){
    const int il = w * 4 + rq;             // local row 0..15
    const int i  = i0 + il;
    const float s1i = s1[b * NN + i];
    const int4* ap = (const int4*)(adj + ((size_t)(b * NN + i)) * NN);

    float sc[16];
    float mx = -3.0e38f;
    #pragma unroll
    for (int c = 0; c < 4; ++c){
      int4 a4 = ap[lane * 4 + c];          // j = lane*16 + 4c ..
      float e0 = s1i + s2r[c*4+0]; e0 = fmaxf(e0, ALPHA_S * e0);
      float e1 = s1i + s2r[c*4+1]; e1 = fmaxf(e1, ALPHA_S * e1);
      float e2 = s1i + s2r[c*4+2]; e2 = fmaxf(e2, ALPHA_S * e2);
      float e3 = s1i + s2r[c*4+3]; e3 = fmaxf(e3, ALPHA_S * e3);
      sc[c*4+0] = a4.x > 0 ? e0 : MASK_VAL;
      sc[c*4+1] = a4.y > 0 ? e1 : MASK_VAL;
      sc[c*4+2] = a4.z > 0 ? e2 : MASK_VAL;
      sc[c*4+3] = a4.w > 0 ? e3 : MASK_VAL;
      mx = fmaxf(mx, fmaxf(fmaxf(sc[c*4+0], sc[c*4+1]), fmaxf(sc[c*4+2], sc[c*4+3])));
    }
    mx = wave_max(mx);

    float psum = 0.f;
    half8 v0, v1;
    #pragma unroll
    for (int m = 0; m < 8; ++m){
      float p = __expf(sc[m] - mx);
      psum += p;
      v0[m] = (_Float16)p;
    }
    #pragma unroll
    for (int m = 0; m < 8; ++m){
      float p = __expf(sc[8 + m] - mx);
      psum += p;
      v1[m] = (_Float16)p;
    }
    psum = wave_sum(psum);
    if (lane == 0) inv_l[il] = 1.0f / psum;

    _Float16* dst = &p_buf[il][lane * 16];
    *(half8*)(dst)     = v0;
    *(half8*)(dst + 8) = v1;
  }
  __syncthreads();

  // ---- Phase B: C(16x16) per wave; A = p_buf rows, B = hT col tile ----
  const int m16 = lane & 15;
  const int g   = lane >> 4;
  const int c0  = w * 16;                  // col tile
  f32x4 acc = {0.f, 0.f, 0.f, 0.f};
  const _Float16* pa = &p_buf[m16][g * 8];
  const size_t bbase = (size_t)b * 65536 + (size_t)(c0 + m16) * 32 + (size_t)g * 8;

  #pragma unroll 4
  for (int kk = 0; kk < 32; ++kk){
    half8 af = *(const half8*)(pa + kk * 32);                    // A[m][kk*32 + g*8 + j]
    half8 bh = *(const half8*)(hT_hi + bbase + (size_t)kk * 2048);
    half8 bl = *(const half8*)(hT_lo + bbase + (size_t)kk * 2048);
    acc = __builtin_amdgcn_mfma_f32_16x16x32_f16(af, bh, acc, 0, 0, 0);
    acc = __builtin_amdgcn_mfma_f32_16x16x32_f16(af, bl, acc, 0, 0, 0);
  }

  #pragma unroll
  for (int q = 0; q < 4; ++q){
    const int row = g * 4 + q;             // C layout: col=lane&15, row=(lane>>4)*4+q
    float v = acc[q] * inv_l[row];
    float o = v > 0.f ? v : __expf(v) - 1.0f;   // ELU (alpha=1)
    out[((size_t)(b * NN + i0 + row)) * FOUT + c0 + m16] = o;
  }
}

extern "C" void kernel_launch(void* const* d_in, const int* in_sizes, int n_in,
                              void* d_out, int out_size, void* d_ws, size_t ws_size,
                              hipStream_t stream) {
  (void)in_sizes; (void)n_in; (void)out_size; (void)ws_size;
  const float* inp = (const float*)d_in[0];   // (16,1024,128) fp32
  const int*   adj = (const int*)d_in[1];     // (16,1024,1024) int32
  const float* W   = (const float*)d_in[2];   // (128,64) fp32
  const float* a   = (const float*)d_in[3];   // (128,1) fp32
  float* outp = (float*)d_out;                // (16,1024,64) fp32

  _Float16* hT_hi = (_Float16*)d_ws;                    // 1,048,576 elems (2 MB)
  _Float16* hT_lo = hT_hi + (size_t)BB * 65536;         // 2 MB
  float* s1 = (float*)(hT_lo + (size_t)BB * 65536);     // 64 KB
  float* s2 = s1 + BB * NN;                             // 64 KB

  k_proj<<<BB * NN / 16, 256, 0, stream>>>(inp, W, a, hT_hi, hT_lo, s1, s2);
  k_attn<<<BB * (NN / 16), 256, 0, stream>>>(adj, hT_hi, hT_lo, s1, s2, outp);
}